// Round 7
// baseline (214.032 us; speedup 1.0000x reference)
//
#include <hip/hip_runtime.h>
#include <hip/hip_bf16.h>
#include <stdint.h>

// NTXentLoss: B=4096, D=512, N=8192, tau=0.07, out = scalar mean loss.
// loss_i = -sim[i, i^B] + M + log( sum_{j != i} exp(sim_ij - M) ),  M = 1/tau
//
// R8 (resubmit -- R8 bench never ran, broker timeout): NO LDS, NO barriers,
// NO inline asm in the K-loop. R4-R7 showed the plateau (~460 TF, MfmaUtil
// 18%, both pipes idle) is invariant to bank conflicts, waitcnt hygiene,
// and LDS aliasing -- the block-wide barrier+drain staging structure itself
// is the cost. K=512 is small: per-wave operand slices are L2-resident, so
// MFMA fragments are loaded DIRECTLY global->VGPR (bf16x8 per lane; quads
// of lanes make 16 rows x 64 B coalesced requests) and the compiler
// pipelines a pure dataflow loop with its own counted waits. Round-0's
// proven geometry + epilogue (128^2 tiles, 2080 triangular blocks, 4 waves,
// wave=64x64, acc[4][4]), launch_bounds(256,3) for ~12 independent
// waves/CU. R4's proven 3-kernel split.

#define N_TOT   8192
#define B_HALF  4096
#define DDIM    512
#define INV_TAU 14.285714285714286f   // 1/0.07 == fixed logsumexp offset M
#define TTILES  64                    // 8192 / 128

typedef __bf16 bf16x8 __attribute__((ext_vector_type(8)));
typedef __bf16 bf16x4 __attribute__((ext_vector_type(4)));
typedef float  floatx4 __attribute__((ext_vector_type(4)));

// ---------------- kernel 1: normalize rows, fp32 -> bf16 z; zero sums/out ---
__global__ __launch_bounds__(256) void knorm(const float* __restrict__ anchor,
                                             const float* __restrict__ positive,
                                             __bf16* __restrict__ z,
                                             float* __restrict__ row_sums,
                                             float* __restrict__ out) {
    const int row  = blockIdx.x * 4 + (threadIdx.x >> 6);
    const int lane = threadIdx.x & 63;
    if (lane == 0) row_sums[row] = 0.0f;   // replaces hipMemsetAsync
    if (blockIdx.x == 0 && threadIdx.x == 0) out[0] = 0.0f;
    const float* src = (row < B_HALF) ? (anchor + (size_t)row * DDIM)
                                      : (positive + (size_t)(row - B_HALF) * DDIM);
    float4 v0 = ((const float4*)src)[lane];
    float4 v1 = ((const float4*)src)[lane + 64];
    float ss = v0.x*v0.x + v0.y*v0.y + v0.z*v0.z + v0.w*v0.w
             + v1.x*v1.x + v1.y*v1.y + v1.z*v1.z + v1.w*v1.w;
    #pragma unroll
    for (int m = 1; m < 64; m <<= 1) ss += __shfl_xor(ss, m, 64);
    const float inv = 1.0f / fmaxf(sqrtf(ss), 1e-8f);
    bf16x4 o0, o1;
    o0[0] = (__bf16)(v0.x*inv); o0[1] = (__bf16)(v0.y*inv);
    o0[2] = (__bf16)(v0.z*inv); o0[3] = (__bf16)(v0.w*inv);
    o1[0] = (__bf16)(v1.x*inv); o1[1] = (__bf16)(v1.y*inv);
    o1[2] = (__bf16)(v1.z*inv); o1[3] = (__bf16)(v1.w*inv);
    bf16x4* dst = (bf16x4*)(z + (size_t)row * DDIM);
    dst[lane]      = o0;
    dst[lane + 64] = o1;
}

// ---------------- kernel 2: upper-triangle 128x128 sim tiles, fused exp-sum --
// Grid 2080 = 64*65/2 tile-pairs (rt <= ct). 256 threads = 4 waves (2x2);
// each wave owns 64x64 of C via acc[4][4] 16x16x32 bf16 fragments. Operands
// read straight from global (L2-hot z panels, XCD-swizzled blockIdx); the
// K-loop is pure dataflow -- the compiler inserts its own counted waits and
// software-pipelines across iterations.
__global__ __launch_bounds__(256, 3) void ksim(const __bf16* __restrict__ z,
                                               float* __restrict__ row_sums,
                                               float* __restrict__ pos_sims) {
    // XCD-chunked bijective swizzle (2080 = 8 * 260), then triangular decode.
    int bid = (int)blockIdx.x;
    bid = (bid & 7) * 260 + (bid >> 3);
    int rem = bid, rt = 0;
    while (rem >= TTILES - rt) { rem -= TTILES - rt; rt++; }
    const int ct = rt + rem;
    const bool diag = (rt == ct);
    const bool posb = (ct == rt + 32);   // pos pair (i, i+4096) lives here

    const int r0 = rt * 128, c0 = ct * 128;
    const int tid  = threadIdx.x;
    const int w    = tid >> 6, lane = tid & 63;
    const int quad = lane >> 4, nlo = lane & 15;
    const int wrow = (w >> 1) * 64, wcol = (w & 1) * 64;

    // per-lane fragment bases: row = base + nlo, k = kt*32 + quad*8.
    // quads 0..3 of the same nlo read contiguous 64 B of one row.
    const __bf16* pa = z + (size_t)(r0 + wrow + nlo) * DDIM + quad * 8;
    const __bf16* pb = z + (size_t)(c0 + wcol + nlo) * DDIM + quad * 8;

    floatx4 acc[4][4];
    #pragma unroll
    for (int a = 0; a < 4; a++)
        #pragma unroll
        for (int b = 0; b < 4; b++) acc[a][b] = (floatx4){0.f, 0.f, 0.f, 0.f};

    #pragma unroll 4
    for (int kt = 0; kt < 16; kt++) {
        bf16x8 af[4], bfr[4];
        #pragma unroll
        for (int mi = 0; mi < 4; mi++)
            af[mi] = *(const bf16x8*)(pa + mi * 16 * DDIM + kt * 32);
        #pragma unroll
        for (int ni = 0; ni < 4; ni++)
            bfr[ni] = *(const bf16x8*)(pb + ni * 16 * DDIM + kt * 32);
        #pragma unroll
        for (int mi = 0; mi < 4; mi++)
            #pragma unroll
            for (int ni = 0; ni < 4; ni++)
                acc[mi][ni] = __builtin_amdgcn_mfma_f32_16x16x32_bf16(
                    af[mi], bfr[ni], acc[mi][ni], 0, 0, 0);
    }

    // epilogue: C/D layout col = lane&15, row = quad*4 + reg (verified r0-R7)
    if (diag) {
        #pragma unroll
        for (int mi = 0; mi < 4; mi++) {
            #pragma unroll
            for (int reg = 0; reg < 4; reg++) {
                const int i = r0 + wrow + mi * 16 + quad * 4 + reg;
                float rs = 0.f;
                #pragma unroll
                for (int ni = 0; ni < 4; ni++) {
                    const int j = c0 + wcol + ni * 16 + nlo;
                    const float e = __expf(acc[mi][ni][reg] * INV_TAU - INV_TAU);
                    rs += (j == i) ? 0.f : e;
                }
                rs += __shfl_xor(rs, 1, 64);
                rs += __shfl_xor(rs, 2, 64);
                rs += __shfl_xor(rs, 4, 64);
                rs += __shfl_xor(rs, 8, 64);
                if (nlo == 0) atomicAdd(&row_sums[i], rs);
            }
        }
    } else {
        float cs[4] = {0.f, 0.f, 0.f, 0.f};   // per-lane col partials
        #pragma unroll
        for (int mi = 0; mi < 4; mi++) {
            #pragma unroll
            for (int reg = 0; reg < 4; reg++) {
                const int i = r0 + wrow + mi * 16 + quad * 4 + reg;
                const int ipos = i ^ B_HALF;
                float rs = 0.f;
                #pragma unroll
                for (int ni = 0; ni < 4; ni++) {
                    const int j = c0 + wcol + ni * 16 + nlo;
                    const float sim = acc[mi][ni][reg] * INV_TAU;
                    const float e = __expf(sim - INV_TAU);
                    if (posb && j == ipos) {        // unique writer per pair
                        pos_sims[i] = sim;
                        pos_sims[j] = sim;
                    }
                    rs += e;
                    cs[ni] += e;
                }
                rs += __shfl_xor(rs, 1, 64);
                rs += __shfl_xor(rs, 2, 64);
                rs += __shfl_xor(rs, 4, 64);
                rs += __shfl_xor(rs, 8, 64);
                if (nlo == 0) atomicAdd(&row_sums[i], rs);
            }
        }
        #pragma unroll
        for (int ni = 0; ni < 4; ni++) {
            float c = cs[ni];
            c += __shfl_xor(c, 16, 64);
            c += __shfl_xor(c, 32, 64);
            if (quad == 0)
                atomicAdd(&row_sums[c0 + wcol + ni * 16 + nlo], c);
        }
    }
}

// ---------------- kernel 3: loss per row + mean (32 blocks, atomic out) -----
__global__ __launch_bounds__(256) void kfinal(const float* __restrict__ row_sums,
                                              const float* __restrict__ pos_sims,
                                              float* __restrict__ out) {
    const int r = blockIdx.x * 256 + threadIdx.x;
    float v = INV_TAU + __logf(row_sums[r]) - pos_sims[r];
    #pragma unroll
    for (int m = 1; m < 64; m <<= 1) v += __shfl_xor(v, m, 64);
    __shared__ float wsum[4];
    if ((threadIdx.x & 63) == 0) wsum[threadIdx.x >> 6] = v;
    __syncthreads();
    if (threadIdx.x == 0)
        atomicAdd(out, (wsum[0] + wsum[1] + wsum[2] + wsum[3]) * (1.0f / (float)N_TOT));
}

extern "C" void kernel_launch(void* const* d_in, const int* in_sizes, int n_in,
                              void* d_out, int out_size, void* d_ws, size_t ws_size,
                              hipStream_t stream) {
    const float* anchor   = (const float*)d_in[0];
    const float* positive = (const float*)d_in[1];
    float* out = (float*)d_out;

    char* ws = (char*)d_ws;
    __bf16* z        = (__bf16*)ws;                        // 8192*512*2 = 8 MB
    float*  row_sums = (float*)(ws + 8388608);             // 32 KB
    float*  pos_sims = (float*)(ws + 8388608 + 32768);     // 32 KB

    knorm<<<N_TOT / 4, 256, 0, stream>>>(anchor, positive, z, row_sums, out);
    ksim<<<2080, 256, 0, stream>>>(z, row_sums, pos_sims);
    kfinal<<<N_TOT / 256, 256, 0, stream>>>(row_sums, pos_sims, out);
}

// Round 9
// 132.312 us; speedup vs baseline: 1.6176x; 1.6176x over previous
//
#include <hip/hip_runtime.h>
#include <hip/hip_bf16.h>
#include <stdint.h>

// NTXentLoss: B=4096, D=512, N=8192, tau=0.07, out = scalar mean loss.
// loss_i = -sim[i, i^B] + M + log( sum_{j != i} exp(sim_ij - M) ),  M = 1/tau
//
// R9 (resubmit -- container failed twice, experiment never ran):
// column-pair-band XCD mapping for B-panel L2 residency. Diagnosis across
// R0-R8: all structures hit a ~7 TB/s effective L2/L3 delivery wall with
// both pipes idle -- exposed panel-miss latency. z = 8 MB > 4 MB per-XCD
// L2, and the old %8 swizzle made each XCD sweep ct across the whole
// triangle (B working set ~5 MB -> L3 misses at every barrier drain).
// New mapping: pair columns (p, 63-p) = 65 blocks; XCD x owns pairs
// {x, x+8, x+16, x+24} (8 x 260 = 2080, bijective). Consecutive blocks in
// a band share ct (B-panel L2-hot for ~33 blocks) and walk rt sequentially.
// ksim loop itself is the round-0 verified 76.6 us kernel, unchanged.
// knorm zeroes row_sums/out (R4-proven); kfinal is 32 blocks + atomicAdd.

#define N_TOT   8192
#define B_HALF  4096
#define DDIM    512
#define INV_TAU 14.285714285714286f   // 1/0.07 == fixed logsumexp offset M

typedef __bf16 bf16x8 __attribute__((ext_vector_type(8)));
typedef __bf16 bf16x4 __attribute__((ext_vector_type(4)));
typedef float  floatx4 __attribute__((ext_vector_type(4)));

__device__ __forceinline__ void gl2lds16(const void* g, void* l) {
    __builtin_amdgcn_global_load_lds(
        (const __attribute__((address_space(1))) void*)g,
        (__attribute__((address_space(3))) void*)l, 16, 0, 0);
}

// ---------------- kernel 1: normalize rows, fp32 -> bf16 z; zero sums/out ---
__global__ __launch_bounds__(256) void knorm(const float* __restrict__ anchor,
                                             const float* __restrict__ positive,
                                             __bf16* __restrict__ z,
                                             float* __restrict__ row_sums,
                                             float* __restrict__ out) {
    const int row  = blockIdx.x * 4 + (threadIdx.x >> 6);
    const int lane = threadIdx.x & 63;
    if (lane == 0) row_sums[row] = 0.0f;   // replaces hipMemsetAsync
    if (blockIdx.x == 0 && threadIdx.x == 0) out[0] = 0.0f;
    const float* src = (row < B_HALF) ? (anchor + (size_t)row * DDIM)
                                      : (positive + (size_t)(row - B_HALF) * DDIM);
    float4 v0 = ((const float4*)src)[lane];
    float4 v1 = ((const float4*)src)[lane + 64];
    float ss = v0.x*v0.x + v0.y*v0.y + v0.z*v0.z + v0.w*v0.w
             + v1.x*v1.x + v1.y*v1.y + v1.z*v1.z + v1.w*v1.w;
    #pragma unroll
    for (int m = 1; m < 64; m <<= 1) ss += __shfl_xor(ss, m, 64);
    const float inv = 1.0f / fmaxf(sqrtf(ss), 1e-8f);
    bf16x4 o0, o1;
    o0[0] = (__bf16)(v0.x*inv); o0[1] = (__bf16)(v0.y*inv);
    o0[2] = (__bf16)(v0.z*inv); o0[3] = (__bf16)(v0.w*inv);
    o1[0] = (__bf16)(v1.x*inv); o1[1] = (__bf16)(v1.y*inv);
    o1[2] = (__bf16)(v1.z*inv); o1[3] = (__bf16)(v1.w*inv);
    bf16x4* dst = (bf16x4*)(z + (size_t)row * DDIM);
    dst[lane]      = o0;
    dst[lane + 64] = o1;
}

// ---------------- kernel 2: upper-triangle sim tiles + fused exp-sum ---------
// 2080 tile-pairs (rt <= ct), 128x128 each. block 256 = 4 waves; each wave
// owns 64x64 of C via 4x4 16x16x32 bf16 fragments, BK=64, rotation-swizzled
// LDS (conflict-free ds_read_b128 with wave-uniform-base contiguous
// global_load_lds). Loop body identical to the verified round-0 kernel;
// only the bid -> (rt,ct) mapping changed (column-pair bands per XCD).
__global__ __launch_bounds__(256) void ksim(const __bf16* __restrict__ z,
                                            float* __restrict__ row_sums,
                                            float* __restrict__ pos_sims) {
    // column-pair-band decode: xcd = bid&7, local l = bid>>3 (0..259);
    // pair pr = xcd + 8*(l/65) in 0..31 -> columns (pr, 63-pr), 65 blocks.
    const int bid = (int)blockIdx.x;
    const int xcd = bid & 7, l = bid >> 3;
    const int pr  = xcd + 8 * (l / 65);
    const int j   = l % 65;
    int rt, ct;
    if (j <= pr) { rt = j;          ct = pr;      }   // column pr: rt = 0..pr
    else         { rt = j - pr - 1; ct = 63 - pr; }   // column 63-pr
    const bool diag = (rt == ct);
    const bool posb = (ct == rt + 32);

    const int r0 = rt * 128, c0 = ct * 128;
    const int tid  = threadIdx.x;
    const int w    = tid >> 6, lane = tid & 63;
    const int quad = lane >> 4, nlo = lane & 15;
    const int wrow = (w >> 1) * 64, wcol = (w & 1) * 64;

    __shared__ __align__(16) char smem[32768];
    char* As = smem;
    char* Bs = smem + 16384;
    const char* Bbase = diag ? As : Bs;   // diag blocks reuse the A tile

    floatx4 acc[4][4];
    #pragma unroll
    for (int a = 0; a < 4; a++)
        #pragma unroll
        for (int b = 0; b < 4; b++) acc[a][b] = (floatx4){0.f, 0.f, 0.f, 0.f};

    const int srow = lane >> 3;   // row within an 8-row staging chunk
    const int p    = lane & 7;    // physical 16B chunk within row

    for (int kb = 0; kb < DDIM; kb += 64) {
        #pragma unroll
        for (int it = 0; it < 4; it++) {
            const int c  = w * 4 + it;          // 8-row chunk id, 0..15
            const int rr = c * 8 + srow;        // tile row 0..127
            const int lc = (p - rr) & 7;        // logical chunk stored at phys p
            gl2lds16(z + (size_t)(r0 + rr) * DDIM + kb + lc * 8, As + c * 1024);
            if (!diag)
                gl2lds16(z + (size_t)(c0 + rr) * DDIM + kb + lc * 8, Bs + c * 1024);
        }
        __syncthreads();

        #pragma unroll
        for (int ks = 0; ks < 2; ks++) {
            bf16x8 af[4], bfr[4];
            #pragma unroll
            for (int mi = 0; mi < 4; mi++) {
                const int rr = wrow + mi * 16 + nlo;
                const int pc = (ks * 4 + quad + rr) & 7;
                af[mi] = *(const bf16x8*)(As + rr * 128 + pc * 16);
            }
            #pragma unroll
            for (int ni = 0; ni < 4; ni++) {
                const int rr = wcol + ni * 16 + nlo;
                const int pc = (ks * 4 + quad + rr) & 7;
                bfr[ni] = *(const bf16x8*)(Bbase + rr * 128 + pc * 16);
            }
            #pragma unroll
            for (int mi = 0; mi < 4; mi++)
                #pragma unroll
                for (int ni = 0; ni < 4; ni++)
                    acc[mi][ni] = __builtin_amdgcn_mfma_f32_16x16x32_bf16(
                        af[mi], bfr[ni], acc[mi][ni], 0, 0, 0);
        }
        __syncthreads();
    }

    // epilogue: C/D layout col = lane&15, row = quad*4 + reg
    if (diag) {
        #pragma unroll
        for (int mi = 0; mi < 4; mi++) {
            #pragma unroll
            for (int reg = 0; reg < 4; reg++) {
                const int i = r0 + wrow + mi * 16 + quad * 4 + reg;
                float rs = 0.f;
                #pragma unroll
                for (int ni = 0; ni < 4; ni++) {
                    const int j2 = c0 + wcol + ni * 16 + nlo;
                    const float e = __expf(acc[mi][ni][reg] * INV_TAU - INV_TAU);
                    rs += (j2 == i) ? 0.f : e;
                }
                rs += __shfl_xor(rs, 1, 64);
                rs += __shfl_xor(rs, 2, 64);
                rs += __shfl_xor(rs, 4, 64);
                rs += __shfl_xor(rs, 8, 64);
                if (nlo == 0) atomicAdd(&row_sums[i], rs);
            }
        }
    } else {
        float cs[4] = {0.f, 0.f, 0.f, 0.f};   // per-lane col partials
        #pragma unroll
        for (int mi = 0; mi < 4; mi++) {
            #pragma unroll
            for (int reg = 0; reg < 4; reg++) {
                const int i = r0 + wrow + mi * 16 + quad * 4 + reg;
                const int ipos = i ^ B_HALF;
                float rs = 0.f;
                #pragma unroll
                for (int ni = 0; ni < 4; ni++) {
                    const int j2 = c0 + wcol + ni * 16 + nlo;
                    const float sim = acc[mi][ni][reg] * INV_TAU;
                    const float e = __expf(sim - INV_TAU);
                    if (posb && j2 == ipos) {       // unique writer per pair
                        pos_sims[i]  = sim;
                        pos_sims[j2] = sim;
                    }
                    rs += e;
                    cs[ni] += e;
                }
                rs += __shfl_xor(rs, 1, 64);
                rs += __shfl_xor(rs, 2, 64);
                rs += __shfl_xor(rs, 4, 64);
                rs += __shfl_xor(rs, 8, 64);
                if (nlo == 0) atomicAdd(&row_sums[i], rs);
            }
        }
        #pragma unroll
        for (int ni = 0; ni < 4; ni++) {
            float c = cs[ni];
            c += __shfl_xor(c, 16, 64);
            c += __shfl_xor(c, 32, 64);
            if (quad == 0)
                atomicAdd(&row_sums[c0 + wcol + ni * 16 + nlo], c);
        }
    }
}

// ---------------- kernel 3: loss per row + mean (32 blocks, atomic out) -----
__global__ __launch_bounds__(256) void kfinal(const float* __restrict__ row_sums,
                                              const float* __restrict__ pos_sims,
                                              float* __restrict__ out) {
    const int r = blockIdx.x * 256 + threadIdx.x;
    float v = INV_TAU + __logf(row_sums[r]) - pos_sims[r];
    #pragma unroll
    for (int m = 1; m < 64; m <<= 1) v += __shfl_xor(v, m, 64);
    __shared__ float wsum[4];
    if ((threadIdx.x & 63) == 0) wsum[threadIdx.x >> 6] = v;
    __syncthreads();
    if (threadIdx.x == 0)
        atomicAdd(out, (wsum[0] + wsum[1] + wsum[2] + wsum[3]) * (1.0f / (float)N_TOT));
}

extern "C" void kernel_launch(void* const* d_in, const int* in_sizes, int n_in,
                              void* d_out, int out_size, void* d_ws, size_t ws_size,
                              hipStream_t stream) {
    const float* anchor   = (const float*)d_in[0];
    const float* positive = (const float*)d_in[1];
    float* out = (float*)d_out;

    char* ws = (char*)d_ws;
    __bf16* z        = (__bf16*)ws;                        // 8192*512*2 = 8 MB
    float*  row_sums = (float*)(ws + 8388608);             // 32 KB
    float*  pos_sims = (float*)(ws + 8388608 + 32768);     // 32 KB

    knorm<<<N_TOT / 4, 256, 0, stream>>>(anchor, positive, z, row_sums, out);
    ksim<<<2080, 256, 0, stream>>>(z, row_sums, pos_sims);
    kfinal<<<N_TOT / 256, 256, 0, stream>>>(row_sums, pos_sims, out);
}

// Round 10
// 129.866 us; speedup vs baseline: 1.6481x; 1.0188x over previous
//
#include <hip/hip_runtime.h>
#include <hip/hip_bf16.h>
#include <stdint.h>

// NTXentLoss: B=4096, D=512, N=8192, tau=0.07, out = scalar mean loss.
// loss_i = -sim[i, i^B] + M + log( sum_{j != i} exp(sim_ij - M) ),  M = 1/tau
//
// R10: XCD-local group-pair scheduling. Nine rounds establish: ksim time is
// insensitive to traffic (R4 halved bytes: nil), conflicts (R4), waitcnt
// hygiene (R6), LDS aliasing (R7); worse without reuse (R8); mildly
// sensitive to mapping (R9, FETCH rose 44->99MB yet -7%). Model: Little's
// law on staging -- each block holds ~4-8KB in flight against a ~700-900cy
// far-L2/L3 latency (z panels live on other XCDs). Fix the LATENCY: split
// 64 tile-rows into 8 groups (1MB z each); enumerate the 36 group-pairs'
// tiles in pair order; XCD s gets the contiguous 260-tile slice s
// (g = (bid&7)*260 + bid>>3). Concurrent window per XCD <= 2 pairs = 4MB
// = its own L2 -> staging becomes L2-hit. Loop body / swizzle / epilogue
// byte-for-byte the verified R9 kernel; launch_bounds(256,4) hint added.

#define N_TOT   8192
#define B_HALF  4096
#define DDIM    512
#define INV_TAU 14.285714285714286f   // 1/0.07 == fixed logsumexp offset M

typedef __bf16 bf16x8 __attribute__((ext_vector_type(8)));
typedef __bf16 bf16x4 __attribute__((ext_vector_type(4)));
typedef float  floatx4 __attribute__((ext_vector_type(4)));

__device__ __forceinline__ void gl2lds16(const void* g, void* l) {
    __builtin_amdgcn_global_load_lds(
        (const __attribute__((address_space(1))) void*)g,
        (__attribute__((address_space(3))) void*)l, 16, 0, 0);
}

// ---------------- kernel 1: normalize rows, fp32 -> bf16 z; zero sums/out ---
__global__ __launch_bounds__(256) void knorm(const float* __restrict__ anchor,
                                             const float* __restrict__ positive,
                                             __bf16* __restrict__ z,
                                             float* __restrict__ row_sums,
                                             float* __restrict__ out) {
    const int row  = blockIdx.x * 4 + (threadIdx.x >> 6);
    const int lane = threadIdx.x & 63;
    if (lane == 0) row_sums[row] = 0.0f;   // replaces hipMemsetAsync
    if (blockIdx.x == 0 && threadIdx.x == 0) out[0] = 0.0f;
    const float* src = (row < B_HALF) ? (anchor + (size_t)row * DDIM)
                                      : (positive + (size_t)(row - B_HALF) * DDIM);
    float4 v0 = ((const float4*)src)[lane];
    float4 v1 = ((const float4*)src)[lane + 64];
    float ss = v0.x*v0.x + v0.y*v0.y + v0.z*v0.z + v0.w*v0.w
             + v1.x*v1.x + v1.y*v1.y + v1.z*v1.z + v1.w*v1.w;
    #pragma unroll
    for (int m = 1; m < 64; m <<= 1) ss += __shfl_xor(ss, m, 64);
    const float inv = 1.0f / fmaxf(sqrtf(ss), 1e-8f);
    bf16x4 o0, o1;
    o0[0] = (__bf16)(v0.x*inv); o0[1] = (__bf16)(v0.y*inv);
    o0[2] = (__bf16)(v0.z*inv); o0[3] = (__bf16)(v0.w*inv);
    o1[0] = (__bf16)(v1.x*inv); o1[1] = (__bf16)(v1.y*inv);
    o1[2] = (__bf16)(v1.z*inv); o1[3] = (__bf16)(v1.w*inv);
    bf16x4* dst = (bf16x4*)(z + (size_t)row * DDIM);
    dst[lane]      = o0;
    dst[lane + 64] = o1;
}

// ---------------- kernel 2: upper-triangle sim tiles + fused exp-sum ---------
// 2080 tile-pairs (rt <= ct), 128x128 each. block 256 = 4 waves; each wave
// owns 64x64 of C via 4x4 16x16x32 bf16 fragments, BK=64, rotation-swizzled
// LDS (conflict-free ds_read_b128 with wave-uniform-base contiguous
// global_load_lds). Loop body identical to the verified R9 kernel; only the
// bid -> (rt,ct) mapping changed (XCD-local group-pair slices).
__global__ __launch_bounds__(256, 4) void ksim(const __bf16* __restrict__ z,
                                               float* __restrict__ row_sums,
                                               float* __restrict__ pos_sims) {
    // g = global tile index ordered by group-pair; XCD s = bid&7 owns the
    // contiguous slice [s*260, (s+1)*260).
    const int bid = (int)blockIdx.x;
    int rem = (bid & 7) * 260 + (bid >> 3);
    int gr = 0, gc = 0;
    for (;;) {                       // <=36 scalar iterations
        const int sz = (gr == gc) ? 36 : 64;
        if (rem < sz) break;
        rem -= sz;
        if (++gc == 8) { gr++; gc = gr; }
    }
    int rt, ct;
    if (gr == gc) {                  // triangular 8x8 sub-block (36 tiles)
        int i = 0;
        while (rem >= 8 - i) { rem -= 8 - i; i++; }
        rt = gr * 8 + i;
        ct = gc * 8 + i + rem;
    } else {                         // full 8x8 (64 tiles)
        rt = gr * 8 + (rem >> 3);
        ct = gc * 8 + (rem & 7);
    }
    const bool diag = (rt == ct);
    const bool posb = (ct == rt + 32);

    const int r0 = rt * 128, c0 = ct * 128;
    const int tid  = threadIdx.x;
    const int w    = tid >> 6, lane = tid & 63;
    const int quad = lane >> 4, nlo = lane & 15;
    const int wrow = (w >> 1) * 64, wcol = (w & 1) * 64;

    __shared__ __align__(16) char smem[32768];
    char* As = smem;
    char* Bs = smem + 16384;
    const char* Bbase = diag ? As : Bs;   // diag blocks reuse the A tile

    floatx4 acc[4][4];
    #pragma unroll
    for (int a = 0; a < 4; a++)
        #pragma unroll
        for (int b = 0; b < 4; b++) acc[a][b] = (floatx4){0.f, 0.f, 0.f, 0.f};

    const int srow = lane >> 3;   // row within an 8-row staging chunk
    const int p    = lane & 7;    // physical 16B chunk within row

    for (int kb = 0; kb < DDIM; kb += 64) {
        #pragma unroll
        for (int it = 0; it < 4; it++) {
            const int c  = w * 4 + it;          // 8-row chunk id, 0..15
            const int rr = c * 8 + srow;        // tile row 0..127
            const int lc = (p - rr) & 7;        // logical chunk stored at phys p
            gl2lds16(z + (size_t)(r0 + rr) * DDIM + kb + lc * 8, As + c * 1024);
            if (!diag)
                gl2lds16(z + (size_t)(c0 + rr) * DDIM + kb + lc * 8, Bs + c * 1024);
        }
        __syncthreads();

        #pragma unroll
        for (int ks = 0; ks < 2; ks++) {
            bf16x8 af[4], bfr[4];
            #pragma unroll
            for (int mi = 0; mi < 4; mi++) {
                const int rr = wrow + mi * 16 + nlo;
                const int pc = (ks * 4 + quad + rr) & 7;
                af[mi] = *(const bf16x8*)(As + rr * 128 + pc * 16);
            }
            #pragma unroll
            for (int ni = 0; ni < 4; ni++) {
                const int rr = wcol + ni * 16 + nlo;
                const int pc = (ks * 4 + quad + rr) & 7;
                bfr[ni] = *(const bf16x8*)(Bbase + rr * 128 + pc * 16);
            }
            #pragma unroll
            for (int mi = 0; mi < 4; mi++)
                #pragma unroll
                for (int ni = 0; ni < 4; ni++)
                    acc[mi][ni] = __builtin_amdgcn_mfma_f32_16x16x32_bf16(
                        af[mi], bfr[ni], acc[mi][ni], 0, 0, 0);
        }
        __syncthreads();
    }

    // epilogue: C/D layout col = lane&15, row = quad*4 + reg
    if (diag) {
        #pragma unroll
        for (int mi = 0; mi < 4; mi++) {
            #pragma unroll
            for (int reg = 0; reg < 4; reg++) {
                const int i = r0 + wrow + mi * 16 + quad * 4 + reg;
                float rs = 0.f;
                #pragma unroll
                for (int ni = 0; ni < 4; ni++) {
                    const int j2 = c0 + wcol + ni * 16 + nlo;
                    const float e = __expf(acc[mi][ni][reg] * INV_TAU - INV_TAU);
                    rs += (j2 == i) ? 0.f : e;
                }
                rs += __shfl_xor(rs, 1, 64);
                rs += __shfl_xor(rs, 2, 64);
                rs += __shfl_xor(rs, 4, 64);
                rs += __shfl_xor(rs, 8, 64);
                if (nlo == 0) atomicAdd(&row_sums[i], rs);
            }
        }
    } else {
        float cs[4] = {0.f, 0.f, 0.f, 0.f};   // per-lane col partials
        #pragma unroll
        for (int mi = 0; mi < 4; mi++) {
            #pragma unroll
            for (int reg = 0; reg < 4; reg++) {
                const int i = r0 + wrow + mi * 16 + quad * 4 + reg;
                const int ipos = i ^ B_HALF;
                float rs = 0.f;
                #pragma unroll
                for (int ni = 0; ni < 4; ni++) {
                    const int j2 = c0 + wcol + ni * 16 + nlo;
                    const float sim = acc[mi][ni][reg] * INV_TAU;
                    const float e = __expf(sim - INV_TAU);
                    if (posb && j2 == ipos) {       // unique writer per pair
                        pos_sims[i]  = sim;
                        pos_sims[j2] = sim;
                    }
                    rs += e;
                    cs[ni] += e;
                }
                rs += __shfl_xor(rs, 1, 64);
                rs += __shfl_xor(rs, 2, 64);
                rs += __shfl_xor(rs, 4, 64);
                rs += __shfl_xor(rs, 8, 64);
                if (nlo == 0) atomicAdd(&row_sums[i], rs);
            }
        }
        #pragma unroll
        for (int ni = 0; ni < 4; ni++) {
            float c = cs[ni];
            c += __shfl_xor(c, 16, 64);
            c += __shfl_xor(c, 32, 64);
            if (quad == 0)
                atomicAdd(&row_sums[c0 + wcol + ni * 16 + nlo], c);
        }
    }
}

// ---------------- kernel 3: loss per row + mean (32 blocks, atomic out) -----
__global__ __launch_bounds__(256) void kfinal(const float* __restrict__ row_sums,
                                              const float* __restrict__ pos_sims,
                                              float* __restrict__ out) {
    const int r = blockIdx.x * 256 + threadIdx.x;
    float v = INV_TAU + __logf(row_sums[r]) - pos_sims[r];
    #pragma unroll
    for (int m = 1; m < 64; m <<= 1) v += __shfl_xor(v, m, 64);
    __shared__ float wsum[4];
    if ((threadIdx.x & 63) == 0) wsum[threadIdx.x >> 6] = v;
    __syncthreads();
    if (threadIdx.x == 0)
        atomicAdd(out, (wsum[0] + wsum[1] + wsum[2] + wsum[3]) * (1.0f / (float)N_TOT));
}

extern "C" void kernel_launch(void* const* d_in, const int* in_sizes, int n_in,
                              void* d_out, int out_size, void* d_ws, size_t ws_size,
                              hipStream_t stream) {
    const float* anchor   = (const float*)d_in[0];
    const float* positive = (const float*)d_in[1];
    float* out = (float*)d_out;

    char* ws = (char*)d_ws;
    __bf16* z        = (__bf16*)ws;                        // 8192*512*2 = 8 MB
    float*  row_sums = (float*)(ws + 8388608);             // 32 KB
    float*  pos_sims = (float*)(ws + 8388608 + 32768);     // 32 KB

    knorm<<<N_TOT / 4, 256, 0, stream>>>(anchor, positive, z, row_sums, out);
    ksim<<<2080, 256, 0, stream>>>(z, row_sums, pos_sims);
    kfinal<<<N_TOT / 256, 256, 0, stream>>>(row_sums, pos_sims, out);
}

// Round 11
// 123.525 us; speedup vs baseline: 1.7327x; 1.0513x over previous
//
#include <hip/hip_runtime.h>
#include <hip/hip_bf16.h>
#include <stdint.h>

// NTXentLoss: B=4096, D=512, N=8192, tau=0.07, out = scalar mean loss.
// loss_i = -sim[i, i^B] + M + log( sum_{j != i} exp(sim_ij - M) ),  M = 1/tau
//
// R11: 256^2 tiles / 16 waves -- halve staged bytes against the ~7.5 TB/s
// staging-delivery wall. Model (fits R0/R8/R9/R10 exactly): ksim time =
// staged bytes / 7.5 TB/s; occupancy, mapping, conflicts, waitcnt hygiene
// all null once the stream is dense. 256^2 tile: (BM+BN)/(BM*BN) halves ->
// 270 MB staged -> ~36 us predicted. R4's 256^2 failed because 8 waves
// (acc=128 VGPR) forced a broken counted pipeline; 16 waves gives acc=64,
// ~110 VGPR <= 128 (launch_bounds(1024,4)), BK=64 double-buffered LDS
// (2 x 64 KB), plain __syncthreads (R0-proven), staging of t+1 issued
// before compute of t so the barrier drain waits on an in-flight transfer.
// LDS rotation swizzle byte-for-byte R0 (conflict-free, 128-B rows).
// Column-pair XCD decode (16 pairs x 33 = 528 = 8 x 66). R4-style LDS
// epilogue reduce (4x fewer atomics).

#define N_TOT   8192
#define B_HALF  4096
#define DDIM    512
#define INV_TAU 14.285714285714286f   // 1/0.07 == fixed logsumexp offset M

typedef __bf16 bf16x8 __attribute__((ext_vector_type(8)));
typedef __bf16 bf16x4 __attribute__((ext_vector_type(4)));
typedef float  floatx4 __attribute__((ext_vector_type(4)));

__device__ __forceinline__ void gl2lds16(const void* g, void* l) {
    __builtin_amdgcn_global_load_lds(
        (const __attribute__((address_space(1))) void*)g,
        (__attribute__((address_space(3))) void*)l, 16, 0, 0);
}

// ---------------- kernel 1: normalize rows, fp32 -> bf16 z; zero sums/out ---
__global__ __launch_bounds__(256) void knorm(const float* __restrict__ anchor,
                                             const float* __restrict__ positive,
                                             __bf16* __restrict__ z,
                                             float* __restrict__ row_sums,
                                             float* __restrict__ out) {
    const int row  = blockIdx.x * 4 + (threadIdx.x >> 6);
    const int lane = threadIdx.x & 63;
    if (lane == 0) row_sums[row] = 0.0f;   // replaces hipMemsetAsync
    if (blockIdx.x == 0 && threadIdx.x == 0) out[0] = 0.0f;
    const float* src = (row < B_HALF) ? (anchor + (size_t)row * DDIM)
                                      : (positive + (size_t)(row - B_HALF) * DDIM);
    float4 v0 = ((const float4*)src)[lane];
    float4 v1 = ((const float4*)src)[lane + 64];
    float ss = v0.x*v0.x + v0.y*v0.y + v0.z*v0.z + v0.w*v0.w
             + v1.x*v1.x + v1.y*v1.y + v1.z*v1.z + v1.w*v1.w;
    #pragma unroll
    for (int m = 1; m < 64; m <<= 1) ss += __shfl_xor(ss, m, 64);
    const float inv = 1.0f / fmaxf(sqrtf(ss), 1e-8f);
    bf16x4 o0, o1;
    o0[0] = (__bf16)(v0.x*inv); o0[1] = (__bf16)(v0.y*inv);
    o0[2] = (__bf16)(v0.z*inv); o0[3] = (__bf16)(v0.w*inv);
    o1[0] = (__bf16)(v1.x*inv); o1[1] = (__bf16)(v1.y*inv);
    o1[2] = (__bf16)(v1.z*inv); o1[3] = (__bf16)(v1.w*inv);
    bf16x4* dst = (bf16x4*)(z + (size_t)row * DDIM);
    dst[lane]      = o0;
    dst[lane + 64] = o1;
}

// ---------------- kernel 2: upper-triangle 256x256 sim tiles, fused exp-sum --
// Grid 528 = 32*33/2 (rt <= ct). 1024 threads = 16 waves (4M x 4N); each
// wave owns 64x64 of C via acc[4][4] 16x16x32 bf16 fragments. BK=64,
// double-buffered (A0/B0, A1/B1), one __syncthreads per K-step, staging of
// step t+1 issued before compute of t. R0 rotation swizzle (mod-8, 128-B
// rows, conflict-free).
__global__ __launch_bounds__(1024, 4) void ksim(const __bf16* __restrict__ z,
                                                float* __restrict__ row_sums,
                                                float* __restrict__ pos_sims) {
    // column-pair decode: 16 pairs (p, 31-p), 33 tiles each; XCD s owns
    // pairs {s, s+8} (66 tiles). Bijective over 528.
    const int bid = (int)blockIdx.x;
    const int xcd = bid & 7, l = bid >> 3;     // l in 0..65
    const int pr  = xcd + 8 * (l / 33);        // pair id 0..15
    const int j   = l % 33;
    int rt, ct;
    if (j <= pr) { rt = j;          ct = pr;      }   // column pr
    else         { rt = j - pr - 1; ct = 31 - pr; }   // column 31-pr
    const bool diag = (rt == ct);
    const bool posb = (ct == rt + 16);   // pos pair (i, i+4096) lives here

    const int r0 = rt * 256, c0 = ct * 256;
    const int tid  = threadIdx.x;
    const int w    = tid >> 6, lane = tid & 63;
    const int quad = lane >> 4, nlo = lane & 15;
    const int wr   = w >> 2,   wc  = w & 3;
    const int wrow = wr * 64,  wcol = wc * 64;

    __shared__ __align__(16) char A0[32768], B0[32768];
    __shared__ __align__(16) char A1[32768], B1[32768];

    floatx4 acc[4][4];
    #pragma unroll
    for (int a = 0; a < 4; a++)
        #pragma unroll
        for (int b = 0; b < 4; b++) acc[a][b] = (floatx4){0.f, 0.f, 0.f, 0.f};

    const int srow = lane >> 3;   // row within an 8-row staging chunk
    const int p    = lane & 7;    // physical 16B chunk within row

    // staging: 256 rows x 128 B per tile = 32 chunks of 8 rows; wave w does
    // chunks w*2, w*2+1. Rotation pre-swizzle on the global source (R0).
#define STG_A(dst, KB) do {                                                     \
        _Pragma("unroll") for (int it = 0; it < 2; it++) {                      \
            const int c  = w * 2 + it;                                          \
            const int rr = c * 8 + srow;                                        \
            const int lc = (p - rr) & 7;                                        \
            gl2lds16(z + (size_t)(r0 + rr) * DDIM + (KB) + lc * 8,              \
                     (dst) + c * 1024);                                         \
        } } while (0)
#define STG_B(dst, KB) do {                                                     \
        _Pragma("unroll") for (int it = 0; it < 2; it++) {                      \
            const int c  = w * 2 + it;                                          \
            const int rr = c * 8 + srow;                                        \
            const int lc = (p - rr) & 7;                                        \
            gl2lds16(z + (size_t)(c0 + rr) * DDIM + (KB) + lc * 8,              \
                     (dst) + c * 1024);                                         \
        } } while (0)

    // K-step: stage t+1 into NXT, compute CUR (2 ks-halves), one barrier.
#define KSTEP(CA, CB, NA, NB, KB_NEXT, DO_STAGE) do {                           \
        if (DO_STAGE) { STG_A(NA, KB_NEXT); if (!diag) STG_B(NB, KB_NEXT); }    \
        const char* Bb_ = diag ? (CA) : (CB);                                   \
        _Pragma("unroll") for (int ks = 0; ks < 2; ks++) {                      \
            bf16x8 af[4], bfr[4];                                               \
            _Pragma("unroll") for (int mi = 0; mi < 4; mi++) {                  \
                const int rr = wrow + mi * 16 + nlo;                            \
                const int pc = (ks * 4 + quad + rr) & 7;                        \
                af[mi] = *(const bf16x8*)((CA) + rr * 128 + pc * 16);           \
            }                                                                   \
            _Pragma("unroll") for (int ni = 0; ni < 4; ni++) {                  \
                const int rr = wcol + ni * 16 + nlo;                            \
                const int pc = (ks * 4 + quad + rr) & 7;                        \
                bfr[ni] = *(const bf16x8*)(Bb_ + rr * 128 + pc * 16);           \
            }                                                                   \
            _Pragma("unroll") for (int mi = 0; mi < 4; mi++)                    \
                _Pragma("unroll") for (int ni = 0; ni < 4; ni++)                \
                    acc[mi][ni] = __builtin_amdgcn_mfma_f32_16x16x32_bf16(      \
                        af[mi], bfr[ni], acc[mi][ni], 0, 0, 0);                 \
        }                                                                       \
        __syncthreads();                                                        \
    } while (0)

    // prologue: stage step 0; sync publishes it.
    STG_A(A0, 0); if (!diag) STG_B(B0, 0);
    __syncthreads();

    KSTEP(A0, B0, A1, B1,  64, 1);
    KSTEP(A1, B1, A0, B0, 128, 1);
    KSTEP(A0, B0, A1, B1, 192, 1);
    KSTEP(A1, B1, A0, B0, 256, 1);
    KSTEP(A0, B0, A1, B1, 320, 1);
    KSTEP(A1, B1, A0, B0, 384, 1);
    KSTEP(A0, B0, A1, B1, 448, 1);
    KSTEP(A1, B1, A0, B0,   0, 0);

    // ---------------- epilogue: exp, exclusions, LDS partial-reduce ----------
    float* rbuf = (float*)A0;              // [256][4] : row partial per wc
    float* cbuf = (float*)(A0 + 4096);     // [256][4] : col partial per wr

    float cs[4] = {0.f, 0.f, 0.f, 0.f};
    #pragma unroll
    for (int mi = 0; mi < 4; mi++) {
        #pragma unroll
        for (int reg = 0; reg < 4; reg++) {
            const int il = wrow + mi * 16 + quad * 4 + reg;      // local row
            const int i  = r0 + il;
            const int ipos = i ^ B_HALF;
            float rs = 0.f;
            #pragma unroll
            for (int ni = 0; ni < 4; ni++) {
                const int j2 = c0 + wcol + ni * 16 + nlo;
                const float sim = acc[mi][ni][reg] * INV_TAU;
                float e = __expf(sim - INV_TAU);
                if (diag && j2 == i) e = 0.f;          // exclude self
                if (posb && j2 == ipos) {              // unique writer per pair
                    pos_sims[i]  = sim;
                    pos_sims[j2] = sim;
                }
                rs += e;
                cs[ni] += e;
            }
            rs += __shfl_xor(rs, 1, 64);
            rs += __shfl_xor(rs, 2, 64);
            rs += __shfl_xor(rs, 4, 64);
            rs += __shfl_xor(rs, 8, 64);
            if (nlo == 0) rbuf[il * 4 + wc] = rs;
        }
    }
    if (!diag) {   // symmetric contribution to column rows (off-diag only)
        #pragma unroll
        for (int ni = 0; ni < 4; ni++) {
            float c = cs[ni];
            c += __shfl_xor(c, 16, 64);
            c += __shfl_xor(c, 32, 64);
            if (quad == 0) cbuf[(wcol + ni * 16 + nlo) * 4 + wr] = c;
        }
    }
    __syncthreads();
    if (tid < 256) {
        const float s = rbuf[tid * 4] + rbuf[tid * 4 + 1]
                      + rbuf[tid * 4 + 2] + rbuf[tid * 4 + 3];
        atomicAdd(&row_sums[r0 + tid], s);
    } else if (tid < 512 && !diag) {
        const int c = tid - 256;
        atomicAdd(&row_sums[c0 + c], cbuf[c * 4] + cbuf[c * 4 + 1]
                                   + cbuf[c * 4 + 2] + cbuf[c * 4 + 3]);
    }
#undef KSTEP
#undef STG_A
#undef STG_B
}

// ---------------- kernel 3: loss per row + mean (32 blocks, atomic out) -----
__global__ __launch_bounds__(256) void kfinal(const float* __restrict__ row_sums,
                                              const float* __restrict__ pos_sims,
                                              float* __restrict__ out) {
    const int r = blockIdx.x * 256 + threadIdx.x;
    float v = INV_TAU + __logf(row_sums[r]) - pos_sims[r];
    #pragma unroll
    for (int m = 1; m < 64; m <<= 1) v += __shfl_xor(v, m, 64);
    __shared__ float wsum[4];
    if ((threadIdx.x & 63) == 0) wsum[threadIdx.x >> 6] = v;
    __syncthreads();
    if (threadIdx.x == 0)
        atomicAdd(out, (wsum[0] + wsum[1] + wsum[2] + wsum[3]) * (1.0f / (float)N_TOT));
}

extern "C" void kernel_launch(void* const* d_in, const int* in_sizes, int n_in,
                              void* d_out, int out_size, void* d_ws, size_t ws_size,
                              hipStream_t stream) {
    const float* anchor   = (const float*)d_in[0];
    const float* positive = (const float*)d_in[1];
    float* out = (float*)d_out;

    char* ws = (char*)d_ws;
    __bf16* z        = (__bf16*)ws;                        // 8192*512*2 = 8 MB
    float*  row_sums = (float*)(ws + 8388608);             // 32 KB
    float*  pos_sims = (float*)(ws + 8388608 + 32768);     // 32 KB

    knorm<<<N_TOT / 4, 256, 0, stream>>>(anchor, positive, z, row_sums, out);
    ksim<<<528, 1024, 0, stream>>>(z, row_sums, pos_sims);
    kfinal<<<N_TOT / 256, 256, 0, stream>>>(row_sums, pos_sims, out);
}